// Round 4
// baseline (252.970 us; speedup 1.0000x reference)
//
#include <hip/hip_runtime.h>

#define N_NODES 20000
#define HID     256
#define DEG     32
#define TOPK    16

typedef __attribute__((ext_vector_type(8))) short short8;
typedef __attribute__((ext_vector_type(4))) float f32x4;

__device__ inline unsigned short f2bf(float f) {
    unsigned u = __float_as_uint(f);
    unsigned r = (u + 0x7FFFu + ((u >> 16) & 1u)) >> 16;  // RNE
    return (unsigned short)r;
}
__device__ inline float bf2f(unsigned short s) {
    return __uint_as_float(((unsigned)s) << 16);
}
__device__ inline float bf_lo(unsigned u) { return __uint_as_float(u << 16); }
__device__ inline float bf_hi(unsigned u) { return __uint_as_float(u & 0xFFFF0000u); }

// ---------------------------------------------------------------------------
// fp32 -> bf16 converters
// ---------------------------------------------------------------------------
__global__ __launch_bounds__(256) void convert_kernel(
    const float* __restrict__ src, unsigned short* __restrict__ dst, int n4)
{
    int i = blockIdx.x * 256 + threadIdx.x;
    if (i < n4) {
        float4 f = ((const float4*)src)[i];
        ushort4 o;
        o.x = f2bf(f.x); o.y = f2bf(f.y); o.z = f2bf(f.z); o.w = f2bf(f.w);
        ((ushort4*)dst)[i] = o;
    }
}

// 4 weight matrices, blockIdx.y selects
__global__ __launch_bounds__(256) void convert_w4_kernel(
    const float* __restrict__ a, const float* __restrict__ b,
    const float* __restrict__ c, const float* __restrict__ d,
    unsigned short* __restrict__ da, unsigned short* __restrict__ db,
    unsigned short* __restrict__ dc, unsigned short* __restrict__ dd)
{
    int y = blockIdx.y;
    const float* src = (y == 0) ? a : (y == 1) ? b : (y == 2) ? c : d;
    unsigned short* dst = (y == 0) ? da : (y == 1) ? db : (y == 2) ? dc : dd;
    int i = blockIdx.x * 256 + threadIdx.x;   // 16384 float4 per weight
    float4 f = ((const float4*)src)[i];
    ushort4 o;
    o.x = f2bf(f.x); o.y = f2bf(f.y); o.z = f2bf(f.z); o.w = f2bf(f.w);
    ((ushort4*)dst)[i] = o;
}

// ---------------------------------------------------------------------------
// bf16 MFMA GEMM body with register-prefetch pipeline.
// C[M,256] = A @ W^T + b. 128x128 tile, BK=64, 256 thr (4 waves), mfma 16x16x32.
// ---------------------------------------------------------------------------
#define PADE 8
template<int RELU, int OUTF32>
__device__ __forceinline__ void gemm_body(
    const unsigned short* __restrict__ A, const unsigned short* __restrict__ W,
    const float* __restrict__ bias, unsigned short* __restrict__ Cb,
    float* __restrict__ Cf, int M, int bx, int by)
{
    __shared__ unsigned short As[128][64 + PADE];
    __shared__ unsigned short Ws[128][64 + PADE];

    const int t    = threadIdx.x;
    const int lane = t & 63;
    const int wave = t >> 6;
    const int wm   = (wave & 1) * 64;
    const int wn   = (wave >> 1) * 64;
    const int rowbase = bx * 128;
    const int colbase = by * 128;

    f32x4 acc[4][4];
    #pragma unroll
    for (int i = 0; i < 4; ++i)
        #pragma unroll
        for (int j = 0; j < 4; ++j)
            acc[i][j] = (f32x4){0.f, 0.f, 0.f, 0.f};

    const int lm = lane & 15;
    const int q8 = (lane >> 4) * 8;

    // staging map: idx = t + 256*cidx -> row = idx>>3, col8 = (idx&7)*8
    const int srow = t >> 3;            // rows this thread touches: srow + 32*cidx
    const int scol = (t & 7) * 8;

    uint4 ra[4], rw[4];
    // preload k0 = 0
    #pragma unroll
    for (int cidx = 0; cidx < 4; ++cidx) {
        int row  = srow + 32 * cidx;
        int grow = rowbase + row;
        ra[cidx] = (grow < M) ? *(const uint4*)(A + (size_t)grow * 256 + scol)
                              : make_uint4(0u, 0u, 0u, 0u);
        rw[cidx] = *(const uint4*)(W + (size_t)(colbase + row) * 256 + scol);
    }

    #pragma unroll
    for (int k0 = 0; k0 < 256; k0 += 64) {
        __syncthreads();   // previous MFMA reads done
        #pragma unroll
        for (int cidx = 0; cidx < 4; ++cidx) {
            int row = srow + 32 * cidx;
            *(uint4*)&As[row][scol] = ra[cidx];
            *(uint4*)&Ws[row][scol] = rw[cidx];
        }
        __syncthreads();

        if (k0 < 192) {   // prefetch next tile while MFMA runs
            #pragma unroll
            for (int cidx = 0; cidx < 4; ++cidx) {
                int row  = srow + 32 * cidx;
                int grow = rowbase + row;
                ra[cidx] = (grow < M)
                    ? *(const uint4*)(A + (size_t)grow * 256 + k0 + 64 + scol)
                    : make_uint4(0u, 0u, 0u, 0u);
                rw[cidx] = *(const uint4*)(W + (size_t)(colbase + row) * 256 + k0 + 64 + scol);
            }
        }

        #pragma unroll
        for (int kk = 0; kk < 64; kk += 32) {
            short8 af[4], bfr[4];
            #pragma unroll
            for (int i = 0; i < 4; ++i)
                af[i] = *(const short8*)&As[wm + i * 16 + lm][kk + q8];
            #pragma unroll
            for (int j = 0; j < 4; ++j)
                bfr[j] = *(const short8*)&Ws[wn + j * 16 + lm][kk + q8];
            #pragma unroll
            for (int i = 0; i < 4; ++i)
                #pragma unroll
                for (int j = 0; j < 4; ++j)
                    acc[i][j] = __builtin_amdgcn_mfma_f32_16x16x32_bf16(
                        af[i], bfr[j], acc[i][j], 0, 0, 0);
        }
    }

    const int lq = lane >> 4;
    #pragma unroll
    for (int j = 0; j < 4; ++j) {
        int col = colbase + wn + j * 16 + lm;
        float bv = bias[col];
        #pragma unroll
        for (int i = 0; i < 4; ++i) {
            #pragma unroll
            for (int r = 0; r < 4; ++r) {
                int row = rowbase + wm + i * 16 + lq * 4 + r;
                if (row < M) {
                    float x = acc[i][j][r] + bv;
                    if (OUTF32) {
                        if (RELU) x = (x >= 0.f) ? x : 0.01f * x;
                        Cf[(size_t)row * 256 + col] = x;
                    } else {
                        Cb[(size_t)row * 256 + col] = f2bf(x);
                    }
                }
            }
        }
    }
}

template<int RELU, int OUTF32>
__global__ __launch_bounds__(256) void gemm_bf16(
    const unsigned short* __restrict__ A, const unsigned short* __restrict__ W,
    const float* __restrict__ bias, unsigned short* __restrict__ Cb,
    float* __restrict__ Cf, int M)
{
    gemm_body<RELU, OUTF32>(A, W, bias, Cb, Cf, M, blockIdx.x, blockIdx.y);
}

__global__ __launch_bounds__(256) void gemm_qkv(
    const unsigned short* __restrict__ A,
    const unsigned short* __restrict__ Wq, const unsigned short* __restrict__ Wk,
    const unsigned short* __restrict__ Wv,
    const float* __restrict__ bq, const float* __restrict__ bk,
    const float* __restrict__ bv,
    unsigned short* __restrict__ Cq, unsigned short* __restrict__ Ck,
    unsigned short* __restrict__ Cv, int M)
{
    const int z = blockIdx.z;
    const unsigned short* W = (z == 0) ? Wq : (z == 1) ? Wk : Wv;
    const float* bias        = (z == 0) ? bq : (z == 1) ? bk : bv;
    unsigned short* C        = (z == 0) ? Cq : (z == 1) ? Ck : Cv;
    gemm_body<0, 0>(A, W, bias, C, nullptr, M, blockIdx.x, blockIdx.y);
}

// ---------------------------------------------------------------------------
// Attention v4: one block (256 thr) per node.
//   score: thread (d=t&31, hh=t>>5), 4x uint4 k slice; softmax over d.
//   v: thread (cg=t&31, dg=t>>5) handles cols cg*8..+7 for neighbors dg+8j,
//      4x uint4 loads PREFETCHED before the score phase (latency hidden).
//      Partial sums -> part[8][256] -> final col reduce.
// ---------------------------------------------------------------------------
__global__ __launch_bounds__(256) void attn_kernel(
    const unsigned short* __restrict__ q, const unsigned short* __restrict__ k,
    const unsigned short* __restrict__ v, const int* __restrict__ nbr,
    const float* __restrict__ ew, unsigned short* __restrict__ agg)
{
    __shared__ float qs[256];
    __shared__ int   nb[32];
    __shared__ float wgt[32];
    __shared__ float att[256];       // [h][d]
    __shared__ float part[8][256];   // [dg][col]

    const int n = blockIdx.x;
    const int t = threadIdx.x;

    qs[t] = bf2f(q[(size_t)n * 256 + t]);

    if (t < 32) {
        nb[t] = nbr[n * 32 + t];
        float my = ew[n * 32 + t];
        int cnt = 0;
        #pragma unroll
        for (int j = 0; j < 32; ++j) {
            float o = __shfl(my, j, 32);
            cnt += (o > my || (o == my && j < t)) ? 1 : 0;
        }
        float w = (cnt < TOPK) ? my : 0.0f;
        float s = w;
        #pragma unroll
        for (int off = 16; off; off >>= 1) s += __shfl_xor(s, off, 32);
        wgt[t] = w / (s + 1e-5f);
    }
    __syncthreads();

    const int d  = t & 31;
    const int hh = t >> 5;
    const int cg = t & 31;     // col group (8 cols)
    const int dg = t >> 5;     // neighbor group (4 nbrs: dg+8j)

    // ---- v prefetch: 4 x uint4; each wave instr reads 2 full 512B rows ----
    uint4 vreg[4];
    #pragma unroll
    for (int j = 0; j < 4; ++j)
        vreg[j] = *(const uint4*)(v + (size_t)nb[dg + 8 * j] * 256 + cg * 8);

    // ---- score ----
    float sc = 0.f;
    {
        const unsigned short* krow = k + (size_t)nb[d] * 256 + hh * 32;
        #pragma unroll
        for (int m = 0; m < 4; ++m) {
            uint4 kv = *(const uint4*)(krow + m * 8);
            float4 qa = *(const float4*)&qs[hh * 32 + m * 8];
            float4 qb = *(const float4*)&qs[hh * 32 + m * 8 + 4];
            sc = fmaf(bf_lo(kv.x), qa.x, sc);
            sc = fmaf(bf_hi(kv.x), qa.y, sc);
            sc = fmaf(bf_lo(kv.y), qa.z, sc);
            sc = fmaf(bf_hi(kv.y), qa.w, sc);
            sc = fmaf(bf_lo(kv.z), qb.x, sc);
            sc = fmaf(bf_hi(kv.z), qb.y, sc);
            sc = fmaf(bf_lo(kv.w), qb.z, sc);
            sc = fmaf(bf_hi(kv.w), qb.w, sc);
        }
    }

    float logit = sc * wgt[d] * 0.17677669529663687f;  // * w / sqrt(32)

    float mx = logit;
    #pragma unroll
    for (int off = 16; off; off >>= 1) mx = fmaxf(mx, __shfl_xor(mx, off, 32));
    float e = expf(logit - mx);
    float ssum = e;
    #pragma unroll
    for (int off = 16; off; off >>= 1) ssum += __shfl_xor(ssum, off, 32);
    att[hh * 32 + d] = e / ssum;
    __syncthreads();

    // ---- v accumulate (8 cols x 4 nbrs), all within head h2 ----
    const int h2 = cg >> 2;
    float a8[8] = {0.f, 0.f, 0.f, 0.f, 0.f, 0.f, 0.f, 0.f};
    #pragma unroll
    for (int j = 0; j < 4; ++j) {
        float aw = att[h2 * 32 + dg + 8 * j];
        uint4 vv = vreg[j];
        a8[0] = fmaf(aw, bf_lo(vv.x), a8[0]);
        a8[1] = fmaf(aw, bf_hi(vv.x), a8[1]);
        a8[2] = fmaf(aw, bf_lo(vv.y), a8[2]);
        a8[3] = fmaf(aw, bf_hi(vv.y), a8[3]);
        a8[4] = fmaf(aw, bf_lo(vv.z), a8[4]);
        a8[5] = fmaf(aw, bf_hi(vv.z), a8[5]);
        a8[6] = fmaf(aw, bf_lo(vv.w), a8[6]);
        a8[7] = fmaf(aw, bf_hi(vv.w), a8[7]);
    }
    *(float4*)&part[dg][cg * 8]     = make_float4(a8[0], a8[1], a8[2], a8[3]);
    *(float4*)&part[dg][cg * 8 + 4] = make_float4(a8[4], a8[5], a8[6], a8[7]);
    __syncthreads();

    float acc = 0.f;
    #pragma unroll
    for (int j = 0; j < 8; ++j) acc += part[j][t];
    agg[(size_t)n * 256 + t] = f2bf(acc);
}

// ---------------------------------------------------------------------------
extern "C" void kernel_launch(void* const* d_in, const int* in_sizes, int n_in,
                              void* d_out, int out_size, void* d_ws, size_t ws_size,
                              hipStream_t stream)
{
    const float* h   = (const float*)d_in[0];
    const int*   nbr = (const int*)  d_in[1];
    const float* ew  = (const float*)d_in[2];
    const float* Wq  = (const float*)d_in[3];
    const float* bq  = (const float*)d_in[4];
    const float* Wk  = (const float*)d_in[5];
    const float* bk  = (const float*)d_in[6];
    const float* Wv  = (const float*)d_in[7];
    const float* bv  = (const float*)d_in[8];
    const float* Wo  = (const float*)d_in[9];
    const float* bo  = (const float*)d_in[10];
    float* out = (float*)d_out;

    const size_t NM = (size_t)N_NODES * HID;   // 5,120,000
    char* ws = (char*)d_ws;
    unsigned short* hb   = (unsigned short*)ws; ws += NM * 2;
    unsigned short* qb   = (unsigned short*)ws; ws += NM * 2;
    unsigned short* kb   = (unsigned short*)ws; ws += NM * 2;
    unsigned short* vb   = (unsigned short*)ws; ws += NM * 2;
    unsigned short* aggb = (unsigned short*)ws; ws += NM * 2;
    unsigned short* Wqb  = (unsigned short*)ws; ws += 65536 * 2;
    unsigned short* Wkb  = (unsigned short*)ws; ws += 65536 * 2;
    unsigned short* Wvb  = (unsigned short*)ws; ws += 65536 * 2;
    unsigned short* Wob  = (unsigned short*)ws; ws += 65536 * 2;

    dim3 blk(256);

    convert_kernel<<<dim3((int)(NM / 4 + 255) / 256), blk, 0, stream>>>(h, hb, (int)(NM / 4));
    convert_w4_kernel<<<dim3(64, 4), blk, 0, stream>>>(Wq, Wk, Wv, Wo, Wqb, Wkb, Wvb, Wob);

    dim3 qkvgrid((N_NODES + 127) / 128, 2, 3);
    gemm_qkv<<<qkvgrid, blk, 0, stream>>>(hb, Wqb, Wkb, Wvb, bq, bk, bv,
                                          qb, kb, vb, N_NODES);

    attn_kernel<<<dim3(N_NODES), blk, 0, stream>>>(qb, kb, vb, nbr, ew, aggb);

    dim3 ogrid((N_NODES + 127) / 128, 2);
    gemm_bf16<1, 1><<<ogrid, blk, 0, stream>>>(aggb, Wob, bo, nullptr, out, N_NODES);
}

// Round 5
// 221.066 us; speedup vs baseline: 1.1443x; 1.1443x over previous
//
#include <hip/hip_runtime.h>

#define N_NODES 20000
#define HID     256
#define DEG     32
#define TOPK    16

typedef __attribute__((ext_vector_type(8))) short short8;
typedef __attribute__((ext_vector_type(4))) float f32x4;

__device__ inline unsigned short f2bf(float f) {
    unsigned u = __float_as_uint(f);
    unsigned r = (u + 0x7FFFu + ((u >> 16) & 1u)) >> 16;  // RNE
    return (unsigned short)r;
}
__device__ inline float bf2f(unsigned short s) {
    return __uint_as_float(((unsigned)s) << 16);
}
__device__ inline float bf_lo(unsigned u) { return __uint_as_float(u << 16); }
__device__ inline float bf_hi(unsigned u) { return __uint_as_float(u & 0xFFFF0000u); }

// ---------------------------------------------------------------------------
// fp32 -> bf16 converters
// ---------------------------------------------------------------------------
__global__ __launch_bounds__(256) void convert_kernel(
    const float* __restrict__ src, unsigned short* __restrict__ dst, int n4)
{
    int i = blockIdx.x * 256 + threadIdx.x;
    if (i < n4) {
        float4 f = ((const float4*)src)[i];
        ushort4 o;
        o.x = f2bf(f.x); o.y = f2bf(f.y); o.z = f2bf(f.z); o.w = f2bf(f.w);
        ((ushort4*)dst)[i] = o;
    }
}

__global__ __launch_bounds__(256) void convert_w4_kernel(
    const float* __restrict__ a, const float* __restrict__ b,
    const float* __restrict__ c, const float* __restrict__ d,
    unsigned short* __restrict__ da, unsigned short* __restrict__ db,
    unsigned short* __restrict__ dc, unsigned short* __restrict__ dd)
{
    int y = blockIdx.y;
    const float* src = (y == 0) ? a : (y == 1) ? b : (y == 2) ? c : d;
    unsigned short* dst = (y == 0) ? da : (y == 1) ? db : (y == 2) ? dc : dd;
    int i = blockIdx.x * 256 + threadIdx.x;
    float4 f = ((const float4*)src)[i];
    ushort4 o;
    o.x = f2bf(f.x); o.y = f2bf(f.y); o.z = f2bf(f.z); o.w = f2bf(f.w);
    ((ushort4*)dst)[i] = o;
}

// ---------------------------------------------------------------------------
// top-16 edge-weight mask + normalize: wgt[n][d] = w_d / (sum w + 1e-5)
// one 32-lane group per node
// ---------------------------------------------------------------------------
__global__ __launch_bounds__(256) void topk_kernel(
    const float* __restrict__ ew, float* __restrict__ wgt)
{
    const int lane = threadIdx.x & 31;
    const int n = blockIdx.x * 8 + (threadIdx.x >> 5);
    float my = ew[n * 32 + lane];
    int cnt = 0;
    #pragma unroll
    for (int j = 0; j < 32; ++j) {
        float o = __shfl(my, j, 32);
        cnt += (o > my || (o == my && j < lane)) ? 1 : 0;
    }
    float w = (cnt < TOPK) ? my : 0.0f;
    float s = w;
    #pragma unroll
    for (int off = 16; off; off >>= 1) s += __shfl_xor(s, off, 32);
    wgt[n * 32 + lane] = w / (s + 1e-5f);
}

// ---------------------------------------------------------------------------
// bf16 MFMA GEMM (round-3 structure, no prefetch).
// C[M,256] = A @ W^T + b. 128x128 tile, BK=64, 256 thr (4 waves), mfma 16x16x32.
// HEADMAJ=1: write C to head-major [8][M][32] (col>>5 selects head).
// ---------------------------------------------------------------------------
#define PADE 8
template<int RELU, int OUTF32, int HEADMAJ>
__device__ __forceinline__ void gemm_body(
    const unsigned short* __restrict__ A, const unsigned short* __restrict__ W,
    const float* __restrict__ bias, unsigned short* __restrict__ Cb,
    float* __restrict__ Cf, int M, int bx, int by)
{
    __shared__ unsigned short As[128][64 + PADE];
    __shared__ unsigned short Ws[128][64 + PADE];

    const int t    = threadIdx.x;
    const int lane = t & 63;
    const int wave = t >> 6;
    const int wm   = (wave & 1) * 64;
    const int wn   = (wave >> 1) * 64;
    const int rowbase = bx * 128;
    const int colbase = by * 128;

    f32x4 acc[4][4];
    #pragma unroll
    for (int i = 0; i < 4; ++i)
        #pragma unroll
        for (int j = 0; j < 4; ++j)
            acc[i][j] = (f32x4){0.f, 0.f, 0.f, 0.f};

    const int lm = lane & 15;
    const int q8 = (lane >> 4) * 8;

    for (int k0 = 0; k0 < 256; k0 += 64) {
        #pragma unroll
        for (int cidx = 0; cidx < 4; ++cidx) {
            int idx = t + 256 * cidx;
            int row = idx >> 3;
            int col = (idx & 7) * 8;
            uint4 av = make_uint4(0u, 0u, 0u, 0u);
            int grow = rowbase + row;
            if (grow < M) av = *(const uint4*)(A + (size_t)grow * 256 + k0 + col);
            *(uint4*)&As[row][col] = av;
            uint4 wv = *(const uint4*)(W + (size_t)(colbase + row) * 256 + k0 + col);
            *(uint4*)&Ws[row][col] = wv;
        }
        __syncthreads();

        #pragma unroll
        for (int kk = 0; kk < 64; kk += 32) {
            short8 af[4], bfr[4];
            #pragma unroll
            for (int i = 0; i < 4; ++i)
                af[i] = *(const short8*)&As[wm + i * 16 + lm][kk + q8];
            #pragma unroll
            for (int j = 0; j < 4; ++j)
                bfr[j] = *(const short8*)&Ws[wn + j * 16 + lm][kk + q8];
            #pragma unroll
            for (int i = 0; i < 4; ++i)
                #pragma unroll
                for (int j = 0; j < 4; ++j)
                    acc[i][j] = __builtin_amdgcn_mfma_f32_16x16x32_bf16(
                        af[i], bfr[j], acc[i][j], 0, 0, 0);
        }
        __syncthreads();
    }

    const int lq = lane >> 4;
    #pragma unroll
    for (int j = 0; j < 4; ++j) {
        int col = colbase + wn + j * 16 + lm;
        float bv = bias[col];
        #pragma unroll
        for (int i = 0; i < 4; ++i) {
            #pragma unroll
            for (int r = 0; r < 4; ++r) {
                int row = rowbase + wm + i * 16 + lq * 4 + r;
                if (row < M) {
                    float x = acc[i][j][r] + bv;
                    if (OUTF32) {
                        if (RELU) x = (x >= 0.f) ? x : 0.01f * x;
                        Cf[(size_t)row * 256 + col] = x;
                    } else if (HEADMAJ) {
                        size_t addr = (size_t)(col >> 5) * ((size_t)N_NODES * 32)
                                    + (size_t)row * 32 + (col & 31);
                        Cb[addr] = f2bf(x);
                    } else {
                        Cb[(size_t)row * 256 + col] = f2bf(x);
                    }
                }
            }
        }
    }
}

template<int RELU, int OUTF32>
__global__ __launch_bounds__(256) void gemm_bf16(
    const unsigned short* __restrict__ A, const unsigned short* __restrict__ W,
    const float* __restrict__ bias, unsigned short* __restrict__ Cb,
    float* __restrict__ Cf, int M)
{
    gemm_body<RELU, OUTF32, 0>(A, W, bias, Cb, Cf, M, blockIdx.x, blockIdx.y);
}

__global__ __launch_bounds__(256) void gemm_qkv(
    const unsigned short* __restrict__ A,
    const unsigned short* __restrict__ Wq, const unsigned short* __restrict__ Wk,
    const unsigned short* __restrict__ Wv,
    const float* __restrict__ bq, const float* __restrict__ bk,
    const float* __restrict__ bv,
    unsigned short* __restrict__ Cq, unsigned short* __restrict__ Ck,
    unsigned short* __restrict__ Cv, int M)
{
    const int z = blockIdx.z;
    const unsigned short* W = (z == 0) ? Wq : (z == 1) ? Wk : Wv;
    const float* bias        = (z == 0) ? bq : (z == 1) ? bk : bv;
    unsigned short* C        = (z == 0) ? Cq : (z == 1) ? Ck : Cv;
    gemm_body<0, 0, 1>(A, W, bias, C, nullptr, M, blockIdx.x, blockIdx.y);
}

// ---------------------------------------------------------------------------
// Attention, head-sharded: head = blockIdx.x & 7 (pins all blocks of one head
// to one XCD under round-robin dispatch -> k/v shard (2.56 MB) is L2-resident).
// q/k/v in head-major [8][N][32]. 32-lane group per node; no LDS, no barriers.
//   lane d: k-dot for neighbor d; width-32 softmax.
//   v phase: lane (dg=lane>>3, cg=lane&7) covers cols cg*4..+3 for nbrs dg+4j,
//   v loads prefetched before the score dot; 2-step butterfly reduce over dg.
// ---------------------------------------------------------------------------
__global__ __launch_bounds__(256) void attn_shard(
    const unsigned short* __restrict__ qh, const unsigned short* __restrict__ kh,
    const unsigned short* __restrict__ vh, const int* __restrict__ nbr,
    const float* __restrict__ wgt, unsigned short* __restrict__ agg)
{
    const int h    = blockIdx.x & 7;
    const int t    = threadIdx.x;
    const int lane = t & 31;
    const int n    = (blockIdx.x >> 3) * 8 + (t >> 5);

    const size_t hbase = (size_t)h * ((size_t)N_NODES * 32);

    const int   nbv = nbr[n * 32 + lane];
    const float w   = wgt[n * 32 + lane];

    const int cg = lane & 7;
    const int dg = lane >> 3;

    // ---- v prefetch: 8 x uint2 (4 bf16 cols) for neighbors dg+4j ----
    int nbj[8];
    #pragma unroll
    for (int j = 0; j < 8; ++j)
        nbj[j] = __shfl(nbv, dg + 4 * j, 32);
    uint2 vreg[8];
    #pragma unroll
    for (int j = 0; j < 8; ++j)
        vreg[j] = *(const uint2*)(vh + hbase + (size_t)nbj[j] * 32 + cg * 4);

    // ---- k row (own neighbor) + q slice (broadcast across group) ----
    const unsigned short* kp = kh + hbase + (size_t)nbv * 32;
    const unsigned short* qp = qh + hbase + (size_t)n * 32;
    uint4 kr[4], qr[4];
    #pragma unroll
    for (int m = 0; m < 4; ++m) {
        kr[m] = *(const uint4*)(kp + m * 8);
        qr[m] = *(const uint4*)(qp + m * 8);
    }

    float sc = 0.f;
    #pragma unroll
    for (int m = 0; m < 4; ++m) {
        uint4 kv = kr[m], qv = qr[m];
        sc = fmaf(bf_lo(kv.x), bf_lo(qv.x), sc);
        sc = fmaf(bf_hi(kv.x), bf_hi(qv.x), sc);
        sc = fmaf(bf_lo(kv.y), bf_lo(qv.y), sc);
        sc = fmaf(bf_hi(kv.y), bf_hi(qv.y), sc);
        sc = fmaf(bf_lo(kv.z), bf_lo(qv.z), sc);
        sc = fmaf(bf_hi(kv.z), bf_hi(qv.z), sc);
        sc = fmaf(bf_lo(kv.w), bf_lo(qv.w), sc);
        sc = fmaf(bf_hi(kv.w), bf_hi(qv.w), sc);
    }

    float logit = sc * w * 0.17677669529663687f;  // * w / sqrt(32)

    float mx = logit;
    #pragma unroll
    for (int off = 16; off; off >>= 1) mx = fmaxf(mx, __shfl_xor(mx, off, 32));
    float e = expf(logit - mx);
    float ssum = e;
    #pragma unroll
    for (int off = 16; off; off >>= 1) ssum += __shfl_xor(ssum, off, 32);
    const float att = e / ssum;   // attention weight for neighbor `lane`

    // ---- v accumulate: 4 cols x 8 neighbors ----
    float a0 = 0.f, a1 = 0.f, a2 = 0.f, a3 = 0.f;
    #pragma unroll
    for (int j = 0; j < 8; ++j) {
        float aw = __shfl(att, dg + 4 * j, 32);
        uint2 vv = vreg[j];
        a0 = fmaf(aw, bf_lo(vv.x), a0);
        a1 = fmaf(aw, bf_hi(vv.x), a1);
        a2 = fmaf(aw, bf_lo(vv.y), a2);
        a3 = fmaf(aw, bf_hi(vv.y), a3);
    }
    a0 += __shfl_xor(a0, 8, 32);  a0 += __shfl_xor(a0, 16, 32);
    a1 += __shfl_xor(a1, 8, 32);  a1 += __shfl_xor(a1, 16, 32);
    a2 += __shfl_xor(a2, 8, 32);  a2 += __shfl_xor(a2, 16, 32);
    a3 += __shfl_xor(a3, 8, 32);  a3 += __shfl_xor(a3, 16, 32);

    if (dg == 0) {
        ushort4 o;
        o.x = f2bf(a0); o.y = f2bf(a1); o.z = f2bf(a2); o.w = f2bf(a3);
        *(ushort4*)(agg + (size_t)n * 256 + h * 32 + cg * 4) = o;
    }
}

// ---------------------------------------------------------------------------
extern "C" void kernel_launch(void* const* d_in, const int* in_sizes, int n_in,
                              void* d_out, int out_size, void* d_ws, size_t ws_size,
                              hipStream_t stream)
{
    const float* h   = (const float*)d_in[0];
    const int*   nbr = (const int*)  d_in[1];
    const float* ew  = (const float*)d_in[2];
    const float* Wq  = (const float*)d_in[3];
    const float* bq  = (const float*)d_in[4];
    const float* Wk  = (const float*)d_in[5];
    const float* bk  = (const float*)d_in[6];
    const float* Wv  = (const float*)d_in[7];
    const float* bv  = (const float*)d_in[8];
    const float* Wo  = (const float*)d_in[9];
    const float* bo  = (const float*)d_in[10];
    float* out = (float*)d_out;

    const size_t NM = (size_t)N_NODES * HID;   // 5,120,000
    char* ws = (char*)d_ws;
    unsigned short* hb   = (unsigned short*)ws; ws += NM * 2;
    unsigned short* qb   = (unsigned short*)ws; ws += NM * 2;   // head-major [8][N][32]
    unsigned short* kb   = (unsigned short*)ws; ws += NM * 2;   // head-major
    unsigned short* vb   = (unsigned short*)ws; ws += NM * 2;   // head-major
    unsigned short* aggb = (unsigned short*)ws; ws += NM * 2;   // row-major [N][256]
    unsigned short* Wqb  = (unsigned short*)ws; ws += 65536 * 2;
    unsigned short* Wkb  = (unsigned short*)ws; ws += 65536 * 2;
    unsigned short* Wvb  = (unsigned short*)ws; ws += 65536 * 2;
    unsigned short* Wob  = (unsigned short*)ws; ws += 65536 * 2;
    float* wgt = (float*)ws;                    ws += (size_t)N_NODES * 32 * 4;

    dim3 blk(256);

    convert_kernel<<<dim3((int)(NM / 4 + 255) / 256), blk, 0, stream>>>(h, hb, (int)(NM / 4));
    convert_w4_kernel<<<dim3(64, 4), blk, 0, stream>>>(Wq, Wk, Wv, Wo, Wqb, Wkb, Wvb, Wob);
    topk_kernel<<<dim3(N_NODES / 8), blk, 0, stream>>>(ew, wgt);

    dim3 qkvgrid((N_NODES + 127) / 128, 2, 3);
    gemm_qkv<<<qkvgrid, blk, 0, stream>>>(hb, Wqb, Wkb, Wvb, bq, bk, bv,
                                          qb, kb, vb, N_NODES);

    attn_shard<<<dim3(8 * (N_NODES / 8)), blk, 0, stream>>>(qb, kb, vb, nbr, wgt, aggb);

    dim3 ogrid((N_NODES + 127) / 128, 2);
    gemm_bf16<1, 1><<<ogrid, blk, 0, stream>>>(aggb, Wob, bo, nullptr, out, N_NODES);
}